// Round 9
// baseline (464.126 us; speedup 1.0000x reference)
//
#include <hip/hip_runtime.h>
#include <hip/hip_bf16.h>
#include <hip/hip_cooperative_groups.h>
#include <math.h>

namespace cg = cooperative_groups;

// Problem constants (B=1)
#define HH 16
#define WW 16
#define DD 16
#define LL 4096          // H*W*Dd
#define CC 48            // d_model
#define DIN 48           // d_inner
#define NN 16            // d_state
#define RR 3             // dt_rank
#define KK 8             // scan directions
#define KD 384           // K*DIN
#define NCH 64           // chunks along L
#define CHL 64           // chunk length
#define NBLK (KK * NCH)  // 512 blocks
#define NTHR 256         // 4 waves; each thread covers 3 (d,n) pairs

// DPP-based 16-lane sum (quad_perm xor1/xor2 + row_ror:4/8). Pure VALU.
__device__ __forceinline__ float dpp_add(float x, const int ctrl_tag) {
    int xi = __float_as_int(x);
    int yi;
    switch (ctrl_tag) {
        case 0: yi = __builtin_amdgcn_update_dpp(0, xi, 0xB1, 0xF, 0xF, true); break; // quad_perm [1,0,3,2]
        case 1: yi = __builtin_amdgcn_update_dpp(0, xi, 0x4E, 0xF, 0xF, true); break; // quad_perm [2,3,0,1]
        case 2: yi = __builtin_amdgcn_update_dpp(0, xi, 0x124, 0xF, 0xF, true); break; // row_ror:4
        default: yi = __builtin_amdgcn_update_dpp(0, xi, 0x128, 0xF, 0xF, true); break; // row_ror:8
    }
    return x + __int_as_float(yi);
}
__device__ __forceinline__ float row16_sum(float p) {
    p = dpp_add(p, 0);
    p = dpp_add(p, 1);
    p = dpp_add(p, 2);
    p = dpp_add(p, 3);
    return p;
}

__device__ __forceinline__ int perm_src(int kperm, int ll) {
    int a = ll >> 8, b2 = (ll >> 4) & 15, c2 = ll & 15;
    switch (kperm) {
        case 0: return ll;                       // (h,w,dd)
        case 1: return b2 * 256 + a * 16 + c2;   // swap h,w
        case 2: return c2 * 256 + b2 * 16 + a;   // swap h,dd
        default: return a * 256 + c2 * 16 + b2;  // swap w,dd
    }
}

// ===== Single cooperative kernel: all stages with grid syncs. ==============
// 512 blocks x 256 threads. Co-residency guaranteed: LDS ~48KB (3/CU),
// threads 8/CU, VGPR<=256 still gives 2/CU => capacity >= 512 always.
// ud/xd tiles persist in LDS from stage 3 to stage 5 (same (k,chunk) block).
__global__ __launch_bounds__(NTHR) void k_all(const float* __restrict__ x,
                                              const float* __restrict__ ipw,
                                              const float* __restrict__ cw,
                                              const float* __restrict__ cb,
                                              const float* __restrict__ xpw,
                                              const float* __restrict__ dtw,
                                              const float* __restrict__ dtb,
                                              const float* __restrict__ A_logs,
                                              const float* __restrict__ Ds,
                                              const float* __restrict__ nw,
                                              const float* __restrict__ nb,
                                              const float* __restrict__ opw,
                                              float* __restrict__ out,
                                              float* __restrict__ xm,
                                              float* __restrict__ z,
                                              float* __restrict__ xc,
                                              float* __restrict__ y2,
                                              float* __restrict__ pa_g,
                                              float* __restrict__ hf_g,
                                              float* __restrict__ h0_g) {
    cg::grid_group grid = cg::this_grid();
    int tid = threadIdx.x;
    int bid = blockIdx.x;
    __shared__ float xt[48 * 68];                  // u tile; reused as y_t in S5
    __shared__ float xd[35 * 65];                  // x_dbl (dts+B+C), persists S3->S5
    __shared__ float2 ud[48 * 68];                 // (u, delta), persists S3->S5
    __shared__ float gbuf[4][49];                  // S6 gate buffer

    // ---- Stage 1: in_proj (3 items/thread; 512*768 == LL*96) ---------------
    {
        int base = bid * 768;
#pragma unroll
        for (int r = 0; r < 3; ++r) {
            int item = base + r * NTHR + tid;
            int e = item % 96, l = item / 96;
            const float4* xr = (const float4*)(x + l * CC);
            const float4* wr = (const float4*)(ipw + e * CC);
            float acc = 0.f;
#pragma unroll
            for (int c4 = 0; c4 < CC / 4; ++c4) {
                float4 a = xr[c4], b = wr[c4];
                acc += a.x * b.x + a.y * b.y + a.z * b.z + a.w * b.w;
            }
            if (e < DIN) xm[e * LL + l] = acc;
            else         z[l * DIN + (e - DIN)] = acc;
        }
    }
    grid.sync();

    // ---- Stage 2: depthwise 3x3x3 conv + bias + SiLU (384 items/block) -----
    {
        int base = bid * 384;
#pragma unroll
        for (int r = 0; r < 2; ++r) {
            int li = r * NTHR + tid;
            if (li < 384) {
                int item = base + li;
                int s = item & (LL - 1), d = item >> 12;
                int dd = s & 15, w = (s >> 4) & 15, h = s >> 8;
                const float* wp = cw + d * 27;
                const float* xp = xm + d * LL;
                float acc = 0.f;
#pragma unroll
                for (int i = -1; i <= 1; ++i) {
                    int hh = h + i; if (hh < 0 || hh > 15) continue;
#pragma unroll
                    for (int j = -1; j <= 1; ++j) {
                        int ww2 = w + j; if (ww2 < 0 || ww2 > 15) continue;
#pragma unroll
                        for (int q = -1; q <= 1; ++q) {
                            int dd2 = dd + q; if (dd2 < 0 || dd2 > 15) continue;
                            acc += wp[(i + 1) * 9 + (j + 1) * 3 + (q + 1)]
                                 * xp[hh * 256 + ww2 * 16 + dd2];
                        }
                    }
                }
                acc += cb[d];
                xc[item] = acc / (1.f + __expf(-acc));
            }
        }
    }
    grid.sync();

    // ---- Stage 3: permuted gather + x_proj GEMM + dt_proj + scan phase 1 ---
    int k = bid >> 6;
    int c = bid & (NCH - 1);
    int l0 = c * CHL;
    int kperm = k & 3, krev = k & 4;
    {
        // gather u tile from natural-layout xc (3072 = 48d x 64i)
#pragma unroll
        for (int r = 0; r < 12; ++r) {
            int item = r * NTHR + tid;
            int d = item >> 6, i = item & 63;
            int lg = l0 + i;
            int ll = krev ? (LL - 1 - lg) : lg;
            xt[d * 68 + i] = xc[d * LL + perm_src(kperm, ll)];
        }
        __syncthreads();
        // GEMM: x_dbl[cc][l] = sum_d u[d][l] * xpw[k][cc][d]  (560 items)
#pragma unroll
        for (int r = 0; r < 3; ++r) {
            int item = r * NTHR + tid;
            if (item < 560) {
                int cc = item % 35, l4 = item / 35;
                const float* wr = xpw + (k * 35 + cc) * DIN;
                float4 acc = {0.f, 0.f, 0.f, 0.f};
#pragma unroll
                for (int d2 = 0; d2 < 48; ++d2) {
                    float4 v = ((const float4*)(xt + d2 * 68))[l4];
                    float w = wr[d2];
                    acc.x += v.x * w; acc.y += v.y * w; acc.z += v.z * w; acc.w += v.w * w;
                }
                float* o = xd + cc * 65 + l4 * 4;
                o[0] = acc.x; o[1] = acc.y; o[2] = acc.z; o[3] = acc.w;
            }
        }
        __syncthreads();
        // delta = softplus(dts @ dtw + bias); pack (u, delta) into LDS
#pragma unroll
        for (int r = 0; r < 12; ++r) {
            int item = r * NTHR + tid;
            int d2 = item >> 6, l = item & 63;
            int gd = k * DIN + d2;
            float v = xd[l] * dtw[gd * 3] + xd[65 + l] * dtw[gd * 3 + 1]
                    + xd[130 + l] * dtw[gd * 3 + 2] + dtb[gd];
            float sp = (v > 20.f) ? v : log1pf(__expf(v));
            ud[d2 * 68 + l] = make_float2(xt[d2 * 68 + l], sp);
        }
        __syncthreads();
        // scan phase 1: 3 independent (d,n) recurrences per thread (ILP)
        int n = tid & 15, dbase = tid >> 4;            // dbase: 0..15
        float A0 = -__expf(A_logs[(k * DIN + dbase) * NN + n]);
        float A1 = -__expf(A_logs[(k * DIN + dbase + 16) * NN + n]);
        float A2 = -__expf(A_logs[(k * DIN + dbase + 32) * NN + n]);
        float h0v = 0.f, h1v = 0.f, h2v = 0.f;
        float p0v = 1.f, p1v = 1.f, p2v = 1.f;
#pragma unroll 4
        for (int i = 0; i < CHL; ++i) {
            float Bv = xd[(3 + n) * 65 + i];
            float2 u0 = ud[dbase * 68 + i];
            float2 u1 = ud[(dbase + 16) * 68 + i];
            float2 u2 = ud[(dbase + 32) * 68 + i];
            float dA0 = __expf(u0.y * A0);
            float dA1 = __expf(u1.y * A1);
            float dA2 = __expf(u2.y * A2);
            h0v = h0v * dA0 + u0.y * u0.x * Bv;
            h1v = h1v * dA1 + u1.y * u1.x * Bv;
            h2v = h2v * dA2 + u2.y * u2.x * Bv;
            p0v *= dA0; p1v *= dA1; p2v *= dA2;
        }
        pa_g[((size_t)(k * DIN + dbase) * 16 + n) * NCH + c] = p0v;
        pa_g[((size_t)(k * DIN + dbase + 16) * 16 + n) * NCH + c] = p1v;
        pa_g[((size_t)(k * DIN + dbase + 32) * 16 + n) * NCH + c] = p2v;
        hf_g[((size_t)(k * DIN + dbase) * 16 + n) * NCH + c] = h0v;
        hf_g[((size_t)(k * DIN + dbase + 16) * 16 + n) * NCH + c] = h1v;
        hf_g[((size_t)(k * DIN + dbase + 32) * 16 + n) * NCH + c] = h2v;
    }
    grid.sync();

    // ---- Stage 4: Kogge-Stone scan of chunk summaries (wave per (gid,n)) ---
    {
        int wavebase = bid * 4 + (tid >> 6);           // 0..2047
        int lane = tid & 63;                           // lane = chunk index
#pragma unroll
        for (int j = 0; j < 3; ++j) {
            int wid = j * 2048 + wavebase;             // 0..6143 = (gid*16+n)
            size_t idx = (size_t)wid * NCH + lane;     // coalesced
            float a = pa_g[idx], b = hf_g[idx];
#pragma unroll
            for (int o = 1; o < 64; o <<= 1) {
                float ap = __shfl_up(a, o, 64);
                float bp = __shfl_up(b, o, 64);
                if (lane >= o) { b = a * bp + b; a = a * ap; }
            }
            float h0 = __shfl_up(b, 1, 64);            // exclusive prefix
            if (lane == 0) h0 = 0.f;
            h0_g[idx] = h0;
        }
    }
    grid.sync();

    // ---- Stage 5: scan phase 3 from persistent LDS; y2 store ---------------
    {
        int n = tid & 15, dbase = tid >> 4;
        float A0 = -__expf(A_logs[(k * DIN + dbase) * NN + n]);
        float A1 = -__expf(A_logs[(k * DIN + dbase + 16) * NN + n]);
        float A2 = -__expf(A_logs[(k * DIN + dbase + 32) * NN + n]);
        float D0 = Ds[k * DIN + dbase];
        float D1 = Ds[k * DIN + dbase + 16];
        float D2 = Ds[k * DIN + dbase + 32];
        float h0v = h0_g[((size_t)(k * DIN + dbase) * 16 + n) * NCH + c];
        float h1v = h0_g[((size_t)(k * DIN + dbase + 16) * 16 + n) * NCH + c];
        float h2v = h0_g[((size_t)(k * DIN + dbase + 32) * 16 + n) * NCH + c];
        float* y_t = xt;                               // reuse xt
#pragma unroll 4
        for (int i = 0; i < CHL; ++i) {
            float Bv = xd[(3 + n) * 65 + i];
            float Cv = xd[(19 + n) * 65 + i];
            float2 u0 = ud[dbase * 68 + i];
            float2 u1 = ud[(dbase + 16) * 68 + i];
            float2 u2 = ud[(dbase + 32) * 68 + i];
            float dA0 = __expf(u0.y * A0);
            float dA1 = __expf(u1.y * A1);
            float dA2 = __expf(u2.y * A2);
            h0v = h0v * dA0 + u0.y * u0.x * Bv;
            h1v = h1v * dA1 + u1.y * u1.x * Bv;
            h2v = h2v * dA2 + u2.y * u2.x * Bv;
            float s0 = row16_sum(h0v * Cv);
            float s1 = row16_sum(h1v * Cv);
            float s2 = row16_sum(h2v * Cv);
            if (n == 0) {
                y_t[dbase * 68 + i] = s0 + D0 * u0.x;
                y_t[(dbase + 16) * 68 + i] = s1 + D1 * u1.x;
                y_t[(dbase + 32) * 68 + i] = s2 + D2 * u2.x;
            }
        }
        __syncthreads();
        // de-permuted store: y2[s][k*48..+47], 192B contiguous (768 f4 items)
#pragma unroll
        for (int r = 0; r < 3; ++r) {
            int item = r * NTHR + tid;
            int g = item >> 6, l = item & 63;          // g: 0..11
            int lg = l0 + l;
            int ll = krev ? (LL - 1 - lg) : lg;
            int s = perm_src(kperm, ll);
            float4 v;
#pragma unroll
            for (int j = 0; j < 4; ++j) (&v.x)[j] = y_t[(g * 4 + j) * 68 + l];
            ((float4*)(y2 + (size_t)s * KD + k * DIN))[g] = v;
        }
    }
    grid.sync();

    // ---- Stage 6: sum dirs + LayerNorm + gate + out_proj (8 s per block) ---
    {
        int wv = tid >> 6, lane = tid & 63;
#pragma unroll
        for (int r = 0; r < 2; ++r) {
            int s = bid * 8 + wv * 2 + r;
            float val = 0.f;
            if (lane < DIN) {
                const float* yp = y2 + (size_t)s * KD + lane;
#pragma unroll
                for (int kk = 0; kk < KK; ++kk) val += yp[kk * DIN];
            }
            float m = val;
#pragma unroll
            for (int o = 32; o >= 1; o >>= 1) m += __shfl_xor(m, o, 64);
            m *= (1.f / 48.f);
            float dv = (lane < DIN) ? (val - m) : 0.f;
            float v2 = dv * dv;
#pragma unroll
            for (int o = 32; o >= 1; o >>= 1) v2 += __shfl_xor(v2, o, 64);
            v2 *= (1.f / 48.f);
            float inv = rsqrtf(v2 + 1e-5f);
            if (lane < DIN) {
                float yn = dv * inv * nw[lane] + nb[lane];
                float zz = z[s * DIN + lane];
                gbuf[wv][lane] = yn * (zz / (1.f + __expf(-zz)));
            }
            __syncthreads();
            if (lane < DIN) {
                const float* wr = opw + lane * DIN;    // out_proj_w[c, e]
                float acc = 0.f;
#pragma unroll
                for (int e = 0; e < DIN; ++e) acc += gbuf[wv][e] * wr[e];
                out[s * CC + lane] = acc;
            }
            __syncthreads();
        }
    }
}

// ======================= Fallback path (proven R7 kernels) ==================
__global__ __launch_bounds__(256) void k_inproj(const float* __restrict__ x,
                                                const float* __restrict__ W,
                                                float* __restrict__ xm,
                                                float* __restrict__ z) {
    int tid = blockIdx.x * 256 + threadIdx.x;
    if (tid >= LL * 96) return;
    int e = tid % 96, l = tid / 96;
    const float4* xr = (const float4*)(x + l * CC);
    const float4* wr = (const float4*)(W + e * CC);
    float acc = 0.f;
#pragma unroll
    for (int c4 = 0; c4 < CC / 4; ++c4) {
        float4 a = xr[c4], b = wr[c4];
        acc += a.x * b.x + a.y * b.y + a.z * b.z + a.w * b.w;
    }
    if (e < DIN) xm[e * LL + l] = acc;
    else         z[l * DIN + (e - DIN)] = acc;
}

__global__ __launch_bounds__(256) void k_conv(const float* __restrict__ xm,
                                              const float* __restrict__ cw,
                                              const float* __restrict__ cb,
                                              float* __restrict__ xc) {
    int tid = blockIdx.x * 256 + threadIdx.x;
    if (tid >= DIN * LL) return;
    int s = tid & (LL - 1), d = tid >> 12;
    int dd = s & 15, w = (s >> 4) & 15, h = s >> 8;
    const float* wp = cw + d * 27;
    const float* xp = xm + d * LL;
    float acc = 0.f;
#pragma unroll
    for (int i = -1; i <= 1; ++i) {
        int hh = h + i; if (hh < 0 || hh > 15) continue;
#pragma unroll
        for (int j = -1; j <= 1; ++j) {
            int ww2 = w + j; if (ww2 < 0 || ww2 > 15) continue;
#pragma unroll
            for (int q = -1; q <= 1; ++q) {
                int dd2 = dd + q; if (dd2 < 0 || dd2 > 15) continue;
                acc += wp[(i + 1) * 9 + (j + 1) * 3 + (q + 1)]
                     * xp[hh * 256 + ww2 * 16 + dd2];
            }
        }
    }
    acc += cb[d];
    xc[tid] = acc / (1.f + __expf(-acc));
}

__global__ __launch_bounds__(768) void k_xscan1(const float* __restrict__ xc,
                                                const float* __restrict__ xpw,
                                                const float* __restrict__ dtw,
                                                const float* __restrict__ dtb,
                                                const float* __restrict__ A_logs,
                                                float* __restrict__ BC,
                                                float* __restrict__ ud_g,
                                                float* __restrict__ pa_g,
                                                float* __restrict__ hf_g) {
    int k = blockIdx.x >> 6;
    int c = blockIdx.x & (NCH - 1);
    int l0 = c * CHL;
    int tid = threadIdx.x;
    __shared__ float xt[48 * 68];
    __shared__ float xd[35 * 65];
    __shared__ float2 ud[48 * 68];
    int kperm = k & 3, krev = k & 4;
#pragma unroll
    for (int r = 0; r < 4; ++r) {
        int item = r * 768 + tid;
        int d = item >> 6, i = item & 63;
        int lg = l0 + i;
        int ll = krev ? (LL - 1 - lg) : lg;
        xt[d * 68 + i] = xc[d * LL + perm_src(kperm, ll)];
    }
    __syncthreads();
    if (tid < 560) {
        int cc = tid % 35, l4 = tid / 35;
        const float* wr = xpw + (k * 35 + cc) * DIN;
        float4 acc = {0.f, 0.f, 0.f, 0.f};
#pragma unroll
        for (int d2 = 0; d2 < 48; ++d2) {
            float4 v = ((const float4*)(xt + d2 * 68))[l4];
            float w = wr[d2];
            acc.x += v.x * w; acc.y += v.y * w; acc.z += v.z * w; acc.w += v.w * w;
        }
        float* o = xd + cc * 65 + l4 * 4;
        o[0] = acc.x; o[1] = acc.y; o[2] = acc.z; o[3] = acc.w;
    }
    __syncthreads();
    if (tid < 512) {
        int l = tid >> 3, q = tid & 7;
        float4 v;
#pragma unroll
        for (int j = 0; j < 4; ++j) (&v.x)[j] = xd[(3 + q * 4 + j) * 65 + l];
        ((float4*)(BC + ((size_t)(k * LL + l0 + l)) * 32))[q] = v;
    }
#pragma unroll
    for (int r = 0; r < 4; ++r) {
        int item = r * 768 + tid;
        int d2 = item >> 6, l = item & 63;
        int gd = k * DIN + d2;
        float v = xd[l] * dtw[gd * 3] + xd[65 + l] * dtw[gd * 3 + 1]
                + xd[130 + l] * dtw[gd * 3 + 2] + dtb[gd];
        float sp = (v > 20.f) ? v : log1pf(__expf(v));
        float u = xt[d2 * 68 + l];
        float2 p = make_float2(u, sp);
        ud[d2 * 68 + l] = p;
        ((float2*)ud_g)[(size_t)gd * LL + l0 + l] = p;
    }
    __syncthreads();
    int d = tid >> 4, n = tid & 15;
    int gid = k * DIN + d;
    float A = -__expf(A_logs[gid * NN + n]);
    float h = 0.f, pa = 1.f;
#pragma unroll 8
    for (int i = 0; i < CHL; ++i) {
        float2 uv = ud[d * 68 + i];
        float Bv = xd[(3 + n) * 65 + i];
        float dA = __expf(uv.y * A);
        h = h * dA + uv.y * uv.x * Bv;
        pa *= dA;
    }
    size_t si = (size_t)gid * (NCH * 16) + c * 16 + n;
    pa_g[si] = pa;
    hf_g[si] = h;
}

__global__ __launch_bounds__(256) void k_scan2(const float* __restrict__ pa_g,
                                               const float* __restrict__ hf_g,
                                               float* __restrict__ h0_g) {
    int t = blockIdx.x * 256 + threadIdx.x;
    if (t >= KD * NN) return;
    int n = t & 15;
    int gid = t >> 4;
    size_t base = (size_t)gid * (NCH * 16) + n;
    float h = 0.f;
#pragma unroll 4
    for (int c = 0; c < NCH; ++c) {
        size_t idx = base + (size_t)c * 16;
        h0_g[idx] = h;
        h = h * pa_g[idx] + hf_g[idx];
    }
}

__global__ __launch_bounds__(768) void k_scan3(const float* __restrict__ ud_g,
                                               const float* __restrict__ BC,
                                               const float* __restrict__ A_logs,
                                               const float* __restrict__ Ds,
                                               const float* __restrict__ h0_g,
                                               float* __restrict__ y2) {
    int k = blockIdx.x >> 6;
    int c = blockIdx.x & (NCH - 1);
    int l0 = c * CHL;
    int tid = threadIdx.x;
    int d = tid >> 4, n = tid & 15;
    int gid = k * DIN + d;
    __shared__ float y_t[48 * 68];
    float A = -__expf(A_logs[gid * NN + n]);
    float Dv = Ds[gid];
    float h = h0_g[(size_t)gid * (NCH * 16) + c * 16 + n];
    const float2* up = ((const float2*)ud_g) + (size_t)gid * LL + l0;
    const float* bp = BC + ((size_t)(k * LL + l0)) * 32 + n;
    const float* cp = bp + 16;
#pragma unroll 8
    for (int i = 0; i < CHL; ++i) {
        float2 uv = up[i];
        float Bv = bp[(size_t)i * 32];
        float Cv = cp[(size_t)i * 32];
        float dA = __expf(uv.y * A);
        h = h * dA + uv.y * uv.x * Bv;
        float p = row16_sum(h * Cv);
        if (n == 0) y_t[d * 68 + i] = p + Dv * uv.x;
    }
    __syncthreads();
    int g = tid >> 6, l = tid & 63;
    int lg = l0 + l;
    int ll = (k & 4) ? (LL - 1 - lg) : lg;
    int s = perm_src(k & 3, ll);
    float4 v;
#pragma unroll
    for (int j = 0; j < 4; ++j) (&v.x)[j] = y_t[(g * 4 + j) * 68 + l];
    ((float4*)(y2 + (size_t)s * KD + k * DIN))[g] = v;
}

__global__ __launch_bounds__(256) void k_final2(const float* __restrict__ y2,
                                                const float* __restrict__ z,
                                                const float* __restrict__ nw,
                                                const float* __restrict__ nb,
                                                const float* __restrict__ opw,
                                                float* __restrict__ out) {
    int wv = threadIdx.x >> 6, lane = threadIdx.x & 63;
    int s = blockIdx.x * 4 + wv;
    __shared__ float g[4][DIN];
    float val = 0.f;
    if (lane < DIN) {
        const float* yp = y2 + (size_t)s * KD + lane;
#pragma unroll
        for (int k = 0; k < KK; ++k) val += yp[k * DIN];
    }
    float m = val;
#pragma unroll
    for (int o = 32; o >= 1; o >>= 1) m += __shfl_xor(m, o, 64);
    m *= (1.f / 48.f);
    float dv = (lane < DIN) ? (val - m) : 0.f;
    float v2 = dv * dv;
#pragma unroll
    for (int o = 32; o >= 1; o >>= 1) v2 += __shfl_xor(v2, o, 64);
    v2 *= (1.f / 48.f);
    float inv = rsqrtf(v2 + 1e-5f);
    if (lane < DIN) {
        float yn = dv * inv * nw[lane] + nb[lane];
        float zz = z[s * DIN + lane];
        g[wv][lane] = yn * (zz / (1.f + __expf(-zz)));
    }
    __syncthreads();
    if (lane < DIN) {
        const float* wr = opw + lane * DIN;
        float acc = 0.f;
#pragma unroll
        for (int e = 0; e < DIN; ++e) acc += g[wv][e] * wr[e];
        out[s * CC + lane] = acc;
    }
}

extern "C" void kernel_launch(void* const* d_in, const int* in_sizes, int n_in,
                              void* d_out, int out_size, void* d_ws, size_t ws_size,
                              hipStream_t stream) {
    const float* x      = (const float*)d_in[0];
    const float* ipw    = (const float*)d_in[1];
    const float* cw     = (const float*)d_in[2];
    const float* cb     = (const float*)d_in[3];
    const float* xpw    = (const float*)d_in[4];
    const float* dtw    = (const float*)d_in[5];
    const float* dtb    = (const float*)d_in[6];
    const float* A_logs = (const float*)d_in[7];
    const float* Ds     = (const float*)d_in[8];
    const float* nw     = (const float*)d_in[9];
    const float* nb     = (const float*)d_in[10];
    const float* opw    = (const float*)d_in[11];
    float* out = (float*)d_out;

    float* ws   = (float*)d_ws;
    float* xm   = ws;                                  // DIN*LL
    float* z    = xm + DIN * LL;                       // LL*DIN
    float* xc   = z + LL * DIN;                        // DIN*LL
    float* y2   = xc + DIN * LL;                       // LL*KD
    float* pa_g = y2 + (size_t)LL * KD;                // KD*NCH*16
    float* hf_g = pa_g + (size_t)KD * NCH * 16;
    float* h0_g = hf_g + (size_t)KD * NCH * 16;
    float* ud_g = h0_g + (size_t)KD * NCH * 16;        // 2*KD*LL (fallback only)
    float* BC   = ud_g + (size_t)2 * KD * LL;          // KK*LL*32 (fallback only)

    void* args[] = {
        (void*)&x, (void*)&ipw, (void*)&cw, (void*)&cb, (void*)&xpw,
        (void*)&dtw, (void*)&dtb, (void*)&A_logs, (void*)&Ds, (void*)&nw,
        (void*)&nb, (void*)&opw, (void*)&out, (void*)&xm, (void*)&z,
        (void*)&xc, (void*)&y2, (void*)&pa_g, (void*)&hf_g, (void*)&h0_g
    };
    hipError_t err = hipLaunchCooperativeKernel((void*)k_all, dim3(NBLK),
                                                dim3(NTHR), args, 0, stream);
    if (err != hipSuccess) {
        // deterministic fallback: proven multi-kernel path
        k_inproj<<<(LL * 96 + 255) / 256, 256, 0, stream>>>(x, ipw, xm, z);
        k_conv<<<(DIN * LL + 255) / 256, 256, 0, stream>>>(xm, cw, cb, xc);
        k_xscan1<<<KK * NCH, 768, 0, stream>>>(xc, xpw, dtw, dtb, A_logs,
                                               BC, ud_g, pa_g, hf_g);
        k_scan2<<<(KD * NN + 255) / 256, 256, 0, stream>>>(pa_g, hf_g, h0_g);
        k_scan3<<<KK * NCH, 768, 0, stream>>>(ud_g, BC, A_logs, Ds, h0_g, y2);
        k_final2<<<LL / 4, 256, 0, stream>>>(y2, z, nw, nb, opw, out);
    }
}

// Round 10
// 180.550 us; speedup vs baseline: 2.5706x; 2.5706x over previous
//
#include <hip/hip_runtime.h>
#include <hip/hip_bf16.h>
#include <math.h>

// Problem constants (B=1)
#define HH 16
#define WW 16
#define DD 16
#define LL 4096          // H*W*Dd
#define CC 48            // d_model
#define DIN 48           // d_inner
#define NN 16            // d_state
#define RR 3             // dt_rank
#define KK 8             // scan directions
#define KD 384           // K*DIN
#define NCH 64           // chunks along L
#define CHL 64           // chunk length

// DPP-based 16-lane sum (quad_perm xor1/xor2 + row_ror:4/8). Pure VALU.
__device__ __forceinline__ float dpp_add(float x, const int ctrl_tag) {
    int xi = __float_as_int(x);
    int yi;
    switch (ctrl_tag) {
        case 0: yi = __builtin_amdgcn_update_dpp(0, xi, 0xB1, 0xF, 0xF, true); break; // quad_perm [1,0,3,2]
        case 1: yi = __builtin_amdgcn_update_dpp(0, xi, 0x4E, 0xF, 0xF, true); break; // quad_perm [2,3,0,1]
        case 2: yi = __builtin_amdgcn_update_dpp(0, xi, 0x124, 0xF, 0xF, true); break; // row_ror:4
        default: yi = __builtin_amdgcn_update_dpp(0, xi, 0x128, 0xF, 0xF, true); break; // row_ror:8
    }
    return x + __int_as_float(yi);
}
__device__ __forceinline__ float row16_sum(float p) {
    p = dpp_add(p, 0);
    p = dpp_add(p, 1);
    p = dpp_add(p, 2);
    p = dpp_add(p, 3);
    return p;
}

__device__ __forceinline__ int perm_src(int kperm, int ll) {
    int a = ll >> 8, b2 = (ll >> 4) & 15, c2 = ll & 15;
    switch (kperm) {
        case 0: return ll;                       // (h,w,dd)
        case 1: return b2 * 256 + a * 16 + c2;   // swap h,w
        case 2: return c2 * 256 + b2 * 16 + a;   // swap h,dd
        default: return a * 256 + c2 * 16 + b2;  // swap w,dd
    }
}

// Shared front end for the two scan kernels: gather u tile (permuted),
// x_proj GEMM into xd, delta = softplus(dt_proj) into dt. All in LDS.
__device__ __forceinline__ void build_tiles(const float* __restrict__ xc,
                                            const float* __restrict__ xpw,
                                            const float* __restrict__ dtw,
                                            const float* __restrict__ dtb,
                                            int k, int l0, int kperm, int krev,
                                            int tid,
                                            float* xt, float* xd, float* dt) {
#pragma unroll
    for (int r = 0; r < 4; ++r) {
        int item = r * 768 + tid;                      // 3072 = 48 d * 64 i
        int d = item >> 6, i = item & 63;
        int lg = l0 + i;
        int ll = krev ? (LL - 1 - lg) : lg;
        xt[d * 68 + i] = xc[d * LL + perm_src(kperm, ll)];
    }
    __syncthreads();
    if (tid < 560) {                                   // 35 c x 16 l4
        int cc = tid % 35, l4 = tid / 35;
        const float* wr = xpw + (k * 35 + cc) * DIN;
        float4 acc = {0.f, 0.f, 0.f, 0.f};
#pragma unroll
        for (int d2 = 0; d2 < 48; ++d2) {
            float4 v = ((const float4*)(xt + d2 * 68))[l4];
            float w = wr[d2];
            acc.x += v.x * w; acc.y += v.y * w; acc.z += v.z * w; acc.w += v.w * w;
        }
        float* o = xd + cc * 65 + l4 * 4;
        o[0] = acc.x; o[1] = acc.y; o[2] = acc.z; o[3] = acc.w;
    }
    __syncthreads();
#pragma unroll
    for (int r = 0; r < 4; ++r) {
        int item = r * 768 + tid;                      // 3072 = 48 d * 64 l
        int d2 = item >> 6, l = item & 63;
        int gd = k * DIN + d2;
        float v = xd[l] * dtw[gd * 3] + xd[65 + l] * dtw[gd * 3 + 1]
                + xd[130 + l] * dtw[gd * 3 + 2] + dtb[gd];
        dt[d2 * 68 + l] = (v > 20.f) ? v : log1pf(__expf(v));
    }
    __syncthreads();
}

// ---------------- Kernel 1: in_proj --------------------------------------
__global__ __launch_bounds__(256) void k_inproj(const float* __restrict__ x,
                                                const float* __restrict__ W,
                                                float* __restrict__ xm,
                                                float* __restrict__ z) {
    int tid = blockIdx.x * 256 + threadIdx.x;          // l*96 + e
    if (tid >= LL * 96) return;
    int e = tid % 96, l = tid / 96;
    const float4* xr = (const float4*)(x + l * CC);
    const float4* wr = (const float4*)(W + e * CC);
    float acc = 0.f;
#pragma unroll
    for (int c4 = 0; c4 < CC / 4; ++c4) {
        float4 a = xr[c4], b = wr[c4];
        acc += a.x * b.x + a.y * b.y + a.z * b.z + a.w * b.w;
    }
    if (e < DIN) xm[e * LL + l] = acc;
    else         z[l * DIN + (e - DIN)] = acc;
}

// ---------------- Kernel 2: depthwise conv + SiLU ------------------------
__global__ __launch_bounds__(256) void k_conv(const float* __restrict__ xm,
                                              const float* __restrict__ cw,
                                              const float* __restrict__ cb,
                                              float* __restrict__ xc) {
    int tid = blockIdx.x * 256 + threadIdx.x;          // d*LL + s
    if (tid >= DIN * LL) return;
    int s = tid & (LL - 1), d = tid >> 12;
    int dd = s & 15, w = (s >> 4) & 15, h = s >> 8;
    const float* wp = cw + d * 27;
    const float* xp = xm + d * LL;
    float acc = 0.f;
#pragma unroll
    for (int i = -1; i <= 1; ++i) {
        int hh = h + i; if (hh < 0 || hh > 15) continue;
#pragma unroll
        for (int j = -1; j <= 1; ++j) {
            int ww2 = w + j; if (ww2 < 0 || ww2 > 15) continue;
#pragma unroll
            for (int q = -1; q <= 1; ++q) {
                int dd2 = dd + q; if (dd2 < 0 || dd2 > 15) continue;
                acc += wp[(i + 1) * 9 + (j + 1) * 3 + (q + 1)]
                     * xp[hh * 256 + ww2 * 16 + dd2];
            }
        }
    }
    acc += cb[d];
    xc[tid] = acc / (1.f + __expf(-acc));
}

// ---- Kernel 3 (K_A): tiles + scan phase 1 -> chunk summaries only. --------
// Summary layout [chunk][k][tid]: K_B's lookback reads are coalesced slabs.
__global__ __launch_bounds__(768) void k_scanA(const float* __restrict__ xc,
                                               const float* __restrict__ xpw,
                                               const float* __restrict__ dtw,
                                               const float* __restrict__ dtb,
                                               const float* __restrict__ A_logs,
                                               float* __restrict__ pa_g,
                                               float* __restrict__ hf_g) {
    int k = blockIdx.x >> 6;
    int c = blockIdx.x & (NCH - 1);
    int l0 = c * CHL;
    int tid = threadIdx.x;
    __shared__ float xt[48 * 68];
    __shared__ float xd[35 * 65];
    __shared__ float dt[48 * 68];
    build_tiles(xc, xpw, dtw, dtb, k, l0, k & 3, k & 4, tid, xt, xd, dt);
    int d = tid >> 4, n = tid & 15;
    int gid = k * DIN + d;
    float A = -__expf(A_logs[gid * NN + n]);
    float h = 0.f, pa = 1.f;
#pragma unroll 8
    for (int i = 0; i < CHL; ++i) {
        float delta = dt[d * 68 + i];
        float u = xt[d * 68 + i];
        float Bv = xd[(3 + n) * 65 + i];
        float dA = __expf(delta * A);
        h = h * dA + delta * u * Bv;
        pa *= dA;
    }
    size_t si = ((size_t)c * KK + k) * 768 + tid;
    pa_g[si] = pa;
    hf_g[si] = h;
}

// ---- Kernel 4 (K_B): tiles again + per-thread prefix + phase 3 + y2. ------
__global__ __launch_bounds__(768) void k_scanB(const float* __restrict__ xc,
                                               const float* __restrict__ xpw,
                                               const float* __restrict__ dtw,
                                               const float* __restrict__ dtb,
                                               const float* __restrict__ A_logs,
                                               const float* __restrict__ Ds,
                                               const float* __restrict__ pa_g,
                                               const float* __restrict__ hf_g,
                                               float* __restrict__ y2) {
    int k = blockIdx.x >> 6;
    int c = blockIdx.x & (NCH - 1);
    int l0 = c * CHL;
    int tid = threadIdx.x;
    int kperm = k & 3, krev = k & 4;
    __shared__ float xt[48 * 68];
    __shared__ float xd[35 * 65];
    __shared__ float dt[48 * 68];
    __shared__ float y_t[48 * 68];
    build_tiles(xc, xpw, dtw, dtb, k, l0, kperm, krev, tid, xt, xd, dt);
    // per-thread serial prefix over predecessor chunk summaries (coalesced)
    float h = 0.f;
    for (int cc = 0; cc < c; ++cc) {
        size_t idx = ((size_t)cc * KK + k) * 768 + tid;
        h = pa_g[idx] * h + hf_g[idx];
    }
    int d = tid >> 4, n = tid & 15;
    int gid = k * DIN + d;
    float A = -__expf(A_logs[gid * NN + n]);
    float Dv = Ds[gid];
#pragma unroll 8
    for (int i = 0; i < CHL; ++i) {
        float delta = dt[d * 68 + i];
        float u = xt[d * 68 + i];
        float Bv = xd[(3 + n) * 65 + i];
        float Cv = xd[(19 + n) * 65 + i];
        float dA = __expf(delta * A);
        h = h * dA + delta * u * Bv;
        float p = row16_sum(h * Cv);
        if (n == 0) y_t[d * 68 + i] = p + Dv * u;
    }
    __syncthreads();
    // de-permuted store: y2[s][k*48..+47], 192B contiguous
    {
        int g = tid >> 6, l = tid & 63;                // g: 0..11
        int lg = l0 + l;
        int ll = krev ? (LL - 1 - lg) : lg;
        int s = perm_src(kperm, ll);
        float4 v;
#pragma unroll
        for (int j = 0; j < 4; ++j) (&v.x)[j] = y_t[(g * 4 + j) * 68 + l];
        ((float4*)(y2 + (size_t)s * KD + k * DIN))[g] = v;
    }
}

// ---- Kernel 5: sum dirs + LayerNorm + gate + out_proj. Wave per s. ---------
__global__ __launch_bounds__(256) void k_final2(const float* __restrict__ y2,
                                                const float* __restrict__ z,
                                                const float* __restrict__ nw,
                                                const float* __restrict__ nb,
                                                const float* __restrict__ opw,
                                                float* __restrict__ out) {
    int wv = threadIdx.x >> 6, lane = threadIdx.x & 63;
    int s = blockIdx.x * 4 + wv;
    __shared__ float g[4][DIN];
    float val = 0.f;
    if (lane < DIN) {
        const float* yp = y2 + (size_t)s * KD + lane;
#pragma unroll
        for (int k = 0; k < KK; ++k) val += yp[k * DIN];
    }
    float m = val;
#pragma unroll
    for (int o = 32; o >= 1; o >>= 1) m += __shfl_xor(m, o, 64);
    m *= (1.f / 48.f);
    float dv = (lane < DIN) ? (val - m) : 0.f;
    float v2 = dv * dv;
#pragma unroll
    for (int o = 32; o >= 1; o >>= 1) v2 += __shfl_xor(v2, o, 64);
    v2 *= (1.f / 48.f);
    float inv = rsqrtf(v2 + 1e-5f);
    if (lane < DIN) {
        float yn = dv * inv * nw[lane] + nb[lane];
        float zz = z[s * DIN + lane];
        g[wv][lane] = yn * (zz / (1.f + __expf(-zz)));
    }
    __syncthreads();
    if (lane < DIN) {
        const float* wr = opw + lane * DIN;            // out_proj_w[c, e]
        float acc = 0.f;
#pragma unroll
        for (int e = 0; e < DIN; ++e) acc += g[wv][e] * wr[e];
        out[s * CC + lane] = acc;
    }
}

extern "C" void kernel_launch(void* const* d_in, const int* in_sizes, int n_in,
                              void* d_out, int out_size, void* d_ws, size_t ws_size,
                              hipStream_t stream) {
    const float* x      = (const float*)d_in[0];
    const float* ipw    = (const float*)d_in[1];
    const float* cw     = (const float*)d_in[2];
    const float* cb     = (const float*)d_in[3];
    const float* xpw    = (const float*)d_in[4];
    const float* dtw    = (const float*)d_in[5];
    const float* dtb    = (const float*)d_in[6];
    const float* A_logs = (const float*)d_in[7];
    const float* Ds     = (const float*)d_in[8];
    const float* nw     = (const float*)d_in[9];
    const float* nb     = (const float*)d_in[10];
    const float* opw    = (const float*)d_in[11];
    float* out = (float*)d_out;

    float* ws   = (float*)d_ws;
    float* xm   = ws;                                  // DIN*LL
    float* z    = xm + DIN * LL;                       // LL*DIN
    float* xc   = z + LL * DIN;                        // DIN*LL
    float* y2   = xc + DIN * LL;                       // LL*KD
    float* pa_g = y2 + (size_t)LL * KD;                // NCH*KK*768
    float* hf_g = pa_g + (size_t)NCH * KK * 768;       // NCH*KK*768

    k_inproj<<<(LL * 96 + 255) / 256, 256, 0, stream>>>(x, ipw, xm, z);
    k_conv<<<(DIN * LL + 255) / 256, 256, 0, stream>>>(xm, cw, cb, xc);
    k_scanA<<<KK * NCH, 768, 0, stream>>>(xc, xpw, dtw, dtb, A_logs, pa_g, hf_g);
    k_scanB<<<KK * NCH, 768, 0, stream>>>(xc, xpw, dtw, dtb, A_logs, Ds,
                                          pa_g, hf_g, y2);
    k_final2<<<LL / 4, 256, 0, stream>>>(y2, z, nw, nb, opw, out);
}